// Round 7
// baseline (236.491 us; speedup 1.0000x reference)
//
#include <hip/hip_runtime.h>

// x: [B=64, C=12, 224, 224] f32; w: [C=12, E=768] f32
// out[b, i*14+j, e] = sum_c (16x16 patch-sum of x[b,c]) * w[c,e]
// Roofline: 154 MB read + 38.5 MB write ~= 29-31 us at achieved fill BW.
// R6: barrier-free. One WAVE owns a patch-pair (16x32 region, full 128 B
// lines) across ALL 12 channels: 24 independent nt loads in flight per
// thread, xor-swizzle reduce (bit-2 preserved: q<4 = left patch, q>=4 =
// right), register epilogue, nt stores. No LDS, no __syncthreads -> no
// block-wide issue gaps. w stays cacheable (reused by every wave).

#define BATCH 64
#define CH    12
#define IMGD  224
#define NP    14          // patches per side
#define NPP   (NP * NP)   // 196
#define EMB   768
#define E4    (EMB / 4)   // 192 float4 per output row

typedef float vfloat4 __attribute__((ext_vector_type(4)));

__global__ __launch_bounds__(256) void dcsp_wave_kernel(
    const float* __restrict__ x,
    const float* __restrict__ w,
    float* __restrict__ out)
{
    const int t    = threadIdx.x;
    const int lane = t & 63;
    const int wave = t >> 6;                       // 0..3

    // wave-task: 64 * 14 * 7 = 6272 patch-pairs
    const int task = blockIdx.x * 4 + wave;
    const int b  = task / (NP * (NP / 2));
    const int r0 = task - b * (NP * (NP / 2));
    const int i  = r0 / (NP / 2);
    const int jj = r0 - i * (NP / 2);

    // lane -> (row-octet r8, col-quad q); 8 lanes = one 128 B line
    const int r8 = lane >> 3;
    const int q  = lane & 7;
    const size_t rowoff0 = (size_t)(i * 16 + r8) * IMGD + (jj * 32 + q * 4);
    const size_t rowoff1 = rowoff0 + (size_t)8 * IMGD;

    // all 12 channels, 2 row-octet loads each: 24 independent nt loads
    float s[CH];
#pragma unroll
    for (int c = 0; c < CH; ++c) {
        const float* __restrict__ base =
            x + (size_t)(b * CH + c) * (IMGD * IMGD);
        const vfloat4 a = __builtin_nontemporal_load(
            reinterpret_cast<const vfloat4*>(base + rowoff0));
        const vfloat4 d = __builtin_nontemporal_load(
            reinterpret_cast<const vfloat4*>(base + rowoff1));
        s[c] = ((a.x + a.y) + (a.z + a.w)) + ((d.x + d.y) + (d.z + d.w));
    }

    // xor reduce over masks {1,2,8,16,32}: sums the 32 lanes sharing lane
    // bit 2 (q<4 -> left patch columns, q>=4 -> right patch columns)
#pragma unroll
    for (int m = 0; m < 5; ++m) {
        const int mask = (1 << m) < 4 ? (1 << m) : (1 << (m + 1)); // 1,2,8,16,32
#pragma unroll
        for (int c = 0; c < CH; ++c)
            s[c] += __shfl_xor(s[c], mask, 64);
    }
    // now every lane holds the full pooled[c] for its half-patch

    // epilogue: 2 patches x 192 float4 = 384 outputs; 6 per lane.
    const int half = q >> 2;                       // 0 = left, 1 = right
    const int lidx = r8 * 4 + (q & 3);             // 0..31 within half
    const int j = jj * 2 + half;
    const vfloat4* __restrict__ w4 = reinterpret_cast<const vfloat4*>(w);
    vfloat4* __restrict__ orow = reinterpret_cast<vfloat4*>(out) +
        ((size_t)(b * NPP) + i * NP + j) * E4;

#pragma unroll
    for (int k = 0; k < 6; ++k) {
        const int e4 = lidx + 32 * k;
        vfloat4 acc = (vfloat4){0.f, 0.f, 0.f, 0.f};
#pragma unroll
        for (int c = 0; c < CH; ++c)
            acc += s[c] * w4[c * E4 + e4];
        __builtin_nontemporal_store(acc, orow + e4);
    }
}

extern "C" void kernel_launch(void* const* d_in, const int* in_sizes, int n_in,
                              void* d_out, int out_size, void* d_ws, size_t ws_size,
                              hipStream_t stream) {
    const float* x = (const float*)d_in[0];
    const float* w = (const float*)d_in[1];
    float* out = (float*)d_out;

    // 64*14*7 = 6272 wave-tasks, 4 waves per 256-thread block
    dcsp_wave_kernel<<<BATCH * NP * (NP / 2) / 4, 256, 0, stream>>>(x, w, out);
}